// Round 16
// baseline (3684.115 us; speedup 1.0000x reference)
//
#include <hip/hip_runtime.h>
#include <math.h>

// ---------------------------------------------------------------------------
// TensorProcessor: conv3d(1,3,1)+bias+relu -> Tucker-HOOI core (8,6,6,6)
// Round 21: 4 HOOI sweeps instead of 5 (the warm-started fixed point is
// converged by sweep 3; accuracy-trim changes have passed every time while
// structural gambles burned rounds). Hedge: interior sweeps back to STEPS=3
// (round-16 proven), final sweep STEPS=4. Everything else byte-identical to
// round 20 (best: 3552us): exact 3-block keigh_init, exact sweep-0 F0 solve,
// dataflow-trimmed init/final tails, transposed-tile grams, 2-stage reduce.
// ---------------------------------------------------------------------------

// ws layout (float offsets)
constexpr long long OFF_T   = 0LL;                 // 26,214,400
constexpr long long OFF_TC  = 26214400LL;          // 6,553,600
constexpr long long OFF_TB  = 32768000LL;          // 1,572,864
constexpr long long OFF_PART= OFF_TC;              // <=6,553,600 (init only)
constexpr long long OFF_P2  = OFF_TB;              // <=524,288 (init only)
constexpr long long OFF_TD0a= OFF_TC;              // mode0 (32,6,6,64)=73,728
constexpr long long OFF_TD0b= OFF_TC + 131072;     // mode0 (32,6,6,6)=6,912
constexpr long long OFF_TD  = OFF_TB + 1000000LL;  // sweep small tensors
constexpr long long OFF_G0  = OFF_TB + 1400000LL;  // 1,024
constexpr long long OFF_G1  = OFF_G0 + 1024;       // 10,000
constexpr long long OFF_G2  = OFF_G1 + 10000;      // 16,384
constexpr long long OFF_G3  = OFF_G2 + 16384;      // 4,096
constexpr long long OFF_F0  = 34340864LL;          // 256
constexpr long long OFF_F1  = OFF_F0 + 256;        // 600
constexpr long long OFF_F2  = OFF_F1 + 600;        // 768
constexpr long long OFF_F3  = OFF_F2 + 768;        // 384

__device__ __forceinline__ float rcp_(float x) { return __builtin_amdgcn_rcpf(x); }

template<int CTRL>
__device__ __forceinline__ float dppmovf(float v) {
  return __int_as_float(__builtin_amdgcn_update_dpp(
      0, __float_as_int(v), CTRL, 0xF, 0xF, true));
}
// sum over 8 consecutive lanes, all-DPP (identical in all 8 lanes)
__device__ __forceinline__ float oct_sum(float v) {
  v += dppmovf<0xB1>(v);    // quad_perm xor1
  v += dppmovf<0x4E>(v);    // quad_perm xor2
  v += dppmovf<0x141>(v);   // row_half_mirror
  return v;
}
// full 64-lane sum, result in all lanes
__device__ __forceinline__ float wave_sum64(float v) {
  v += dppmovf<0xB1>(v);
  v += dppmovf<0x4E>(v);
  v += dppmovf<0x124>(v);   // row_ror:4
  v += dppmovf<0x128>(v);   // row_ror:8
  v += __shfl_xor(v, 16, 64);
  v += __shfl_xor(v, 32, 64);
  return v;
}

// ---------------- conv + relu ----------------
__global__ void kconv(const float* __restrict__ x, const float* __restrict__ cw,
                      const float* __restrict__ cb, float* __restrict__ t) {
  int idx = blockIdx.x * blockDim.x + threadIdx.x;
  if (idx >= 26214400) return;
  int w  = idx & 63;
  int h  = (idx >> 6) & 127;
  int d  = (idx >> 13) % 100;
  int o  = idx / 819200;
  float acc = cb[o];
#pragma unroll
  for (int i = 0; i < 4; ++i) {
    const float* xi = x + (((long long)i * 100 + d) * 130 + h) * 64 + w;
#pragma unroll
    for (int kh = 0; kh < 3; ++kh)
      acc = fmaf(cw[(o * 4 + i) * 3 + kh], xi[kh * 64], acc);
  }
  t[idx] = fmaxf(acc, 0.f);
}

// ---------------- big gram (init HOSVD): G = X X^T over fibers ----------------
template<int D, long long QQ, bool TRANS>
__global__ void kgram_big(const float* __restrict__ T, float* __restrict__ part,
                          int P) {
  constexpr int C = 64;
  constexpr int SUB = (D + 63) / 64;
  constexpr int DP = SUB * 64;
  constexpr int STR = DP + 4;                // 16B-aligned float stride
  __shared__ float tile[C * STR];
  const int tid = threadIdx.x;               // 256
  const int ta = tid >> 4, tb = tid & 15;
  float acc[SUB][SUB][4][4];
#pragma unroll
  for (int a = 0; a < SUB; ++a)
#pragma unroll
    for (int b = 0; b < SUB; ++b)
#pragma unroll
      for (int i = 0; i < 4; ++i)
#pragma unroll
        for (int j = 0; j < 4; ++j) acc[a][b][i][j] = 0.f;

  const long long nfib = (long long)P * QQ;
  const int nchunk = (int)(nfib / C);
  for (int ch = blockIdx.x; ch < nchunk; ch += gridDim.x) {
    const long long base = (long long)ch * C;
    __syncthreads();
    if (TRANS) {
      for (int e = tid; e < D * C; e += 256) {
        int a = e & 63, cc = e >> 6;         // a fast -> global coalesced
        tile[cc * STR + a] = T[base * D + e];
      }
    } else {
      for (int e = tid; e < DP * C; e += 256) {
        int cc = e & 63, a = e >> 6;         // cc fast -> global coalesced
        float v = 0.f;
        if (a < D) {
          long long f = base + cc;
          long long p = f / QQ, q = f - p * QQ;   // compile-time QQ
          v = T[(p * D + a) * QQ + q];
        }
        tile[cc * STR + a] = v;
      }
    }
    __syncthreads();
    for (int cc = 0; cc < C; ++cc) {
      const float* tr = &tile[cc * STR];
      float4 av[SUB], bv[SUB];
#pragma unroll
      for (int si = 0; si < SUB; ++si) av[si] = *(const float4*)&tr[si * 64 + ta * 4];
#pragma unroll
      for (int sj = 0; sj < SUB; ++sj) bv[sj] = *(const float4*)&tr[sj * 64 + tb * 4];
#pragma unroll
      for (int si = 0; si < SUB; ++si)
#pragma unroll
        for (int sj = 0; sj < SUB; ++sj) {
          const float a0 = av[si].x, a1 = av[si].y, a2 = av[si].z, a3 = av[si].w;
          const float b0 = bv[sj].x, b1 = bv[sj].y, b2 = bv[sj].z, b3 = bv[sj].w;
          acc[si][sj][0][0] = fmaf(a0, b0, acc[si][sj][0][0]);
          acc[si][sj][0][1] = fmaf(a0, b1, acc[si][sj][0][1]);
          acc[si][sj][0][2] = fmaf(a0, b2, acc[si][sj][0][2]);
          acc[si][sj][0][3] = fmaf(a0, b3, acc[si][sj][0][3]);
          acc[si][sj][1][0] = fmaf(a1, b0, acc[si][sj][1][0]);
          acc[si][sj][1][1] = fmaf(a1, b1, acc[si][sj][1][1]);
          acc[si][sj][1][2] = fmaf(a1, b2, acc[si][sj][1][2]);
          acc[si][sj][1][3] = fmaf(a1, b3, acc[si][sj][1][3]);
          acc[si][sj][2][0] = fmaf(a2, b0, acc[si][sj][2][0]);
          acc[si][sj][2][1] = fmaf(a2, b1, acc[si][sj][2][1]);
          acc[si][sj][2][2] = fmaf(a2, b2, acc[si][sj][2][2]);
          acc[si][sj][2][3] = fmaf(a2, b3, acc[si][sj][2][3]);
          acc[si][sj][3][0] = fmaf(a3, b0, acc[si][sj][3][0]);
          acc[si][sj][3][1] = fmaf(a3, b1, acc[si][sj][3][1]);
          acc[si][sj][3][2] = fmaf(a3, b2, acc[si][sj][3][2]);
          acc[si][sj][3][3] = fmaf(a3, b3, acc[si][sj][3][3]);
        }
    }
  }
  float* pb = part + (long long)blockIdx.x * D * D;
  for (int si = 0; si < SUB; ++si)
    for (int i = 0; i < 4; ++i) {
      int a = si * 64 + ta * 4 + i;
      if (a >= D) continue;
      for (int sj = 0; sj < SUB; ++sj)
        for (int j = 0; j < 4; ++j) {
          int b = sj * 64 + tb * 4 + j;
          if (b >= D) continue;
          pb[a * D + b] = acc[si][sj][i][j];
        }
    }
}

// two-stage reduce: stage1 sums a 1/K slice of b per (k,i); stage2 sums K.
#define RED_K 32
__global__ void kreduce1(const float* __restrict__ part, float* __restrict__ part2,
                         int DD, int nblk) {
  int nb = (DD + 255) >> 8;
  int k = blockIdx.x / nb;
  int i = (blockIdx.x - k * nb) * 256 + threadIdx.x;
  if (i >= DD) return;
  int b0 = (int)((long long)k * nblk / RED_K);
  int b1 = (int)((long long)(k + 1) * nblk / RED_K);
  float s = 0.f;
  for (int b = b0; b < b1; ++b) s += part[(long long)b * DD + i];
  part2[(long long)k * DD + i] = s;
}
__global__ void kreduce2(const float* __restrict__ part2, float* __restrict__ G,
                         int DD) {
  int i = blockIdx.x * 256 + threadIdx.x;
  if (i >= DD) return;
  float s = 0.f;
#pragma unroll 8
  for (int k = 0; k < RED_K; ++k) s += part2[(long long)k * DD + i];
  G[i] = s;
}

// ---------------- small gram (projected Y) ----------------
__global__ void kgram_small(const float* __restrict__ Y, float* __restrict__ G,
                            int P, int d, int Q) {
  int pair = blockIdx.x * blockDim.x + threadIdx.x;
  if (pair >= d * d) return;
  int a = pair / d, b = pair % d;
  float s = 0.f;
  for (int p = 0; p < P; ++p) {
    const float* ya = Y + ((long long)p * d + a) * Q;
    const float* yb = Y + ((long long)p * d + b) * Q;
    for (int q = 0; q < Q; ++q) s = fmaf(ya[q], yb[q], s);
  }
  G[pair] = s;
}

// ---------------- mode contraction: out[p,j,q] = sum_a F[a,j] in[p,a,q] ----------------
template<int R, long long QV>
__global__ void kcontract(const float* __restrict__ in, const float* __restrict__ F,
                          float* __restrict__ out, int P, int d) {
  long long total = (long long)P * QV;
  long long idx = (long long)blockIdx.x * blockDim.x + threadIdx.x;
  if (idx >= total) return;
  long long p = idx / QV, q = idx - p * QV;
  float acc[R];
#pragma unroll
  for (int j = 0; j < R; ++j) acc[j] = 0.f;
  const float* ip = in + (p * d) * QV + q;
  for (int a = 0; a < d; ++a) {
    float v = ip[(long long)a * QV];
#pragma unroll
    for (int j = 0; j < R; ++j) acc[j] = fmaf(F[a * R + j], v, acc[j]);
  }
  float* op = out + (p * R) * QV + q;
#pragma unroll
  for (int j = 0; j < R; ++j) op[(long long)j * QV] = acc[j];
}

// ---------------- eigh: top-r eigenvectors of symmetric G (n<=128) ----------------
struct __align__(16) ESm {
  float ApkL[8256];              // packed-lower Householder columns (export)
  float colbuf[128];             // current pivot column (16B-aligned)
  float wwf[128];                // w_pre vector
  float slv[8][516];             // invit solver: float4 {u0,u1,u2,-} per i
  float dd[128], ee[128], e2s[128], taus[128], scls[128];
  float vt[8][132];
  float lam[8];
  float sca[4];
};

template<int N, int RR, int TH>
__device__ void eig_body(ESm& S, const float* __restrict__ G, float* __restrict__ F) {
  constexpr int NP  = (N <= 32) ? 32 : ((N <= 64) ? 64 : 128);
  constexpr int QL  = NP / 8;          // floats per thread segment (4/8/16)
  constexpr int NC4 = QL / 4;          // float4 chunks per segment (1/2/4)
  constexpr int W   = TH / 64;         // waves in block
  const int tid  = threadIdx.x;
  const int lane = tid & 63, wv = tid >> 6;
  const int q    = tid & 7;            // 8 adjacent lanes share a row
  const int row  = tid >> 3;
  const bool actR = (row < N);
  const int l0 = q * QL;
  const int wrow0 = wv << 3;           // 8 rows per wave

  float4* cb4 = (float4*)S.colbuf;
  float4* ww4 = (float4*)S.wwf;

  // ---- load: thread (row,q) owns A[row][l0 .. l0+QL) in VGPRs ----
  float Ar[QL];
#pragma unroll
  for (int j = 0; j < QL; ++j) Ar[j] = 0.f;
  if (actR) {
#pragma unroll
    for (int j = 0; j < QL; ++j) { int l = l0 + j; if (l < N) Ar[j] = G[row * N + l]; }
  }
  if (row == 0) {                      // colbuf <- column 0 = row 0 (pads exact 0)
#pragma unroll
    for (int c = 0; c < NC4; ++c)
      cb4[(l0 >> 2) + c] = make_float4(Ar[4*c], Ar[4*c+1], Ar[4*c+2], Ar[4*c+3]);
  }
  __syncthreads();

  // ---- Householder tridiagonalization (LAPACK slarfg conventions) ----
  for (int i = 0; i <= N - 3; ++i) {
    const bool wact = (wrow0 + 7 >= i + 1) && (wrow0 <= N - 1);
    float tau_i = 0.f, u_row = 0.f, w_pre = 0.f;
    float ul[QL];
    if (wact) {
      float cbs[QL];
#pragma unroll
      for (int c = 0; c < NC4; ++c) {
        float4 t = cb4[(l0 >> 2) + c];
        cbs[4*c] = t.x; cbs[4*c+1] = t.y; cbs[4*c+2] = t.z; cbs[4*c+3] = t.w;
      }
      float alpha = S.colbuf[i + 1];
      float myc   = S.colbuf[row];

      float nrm = 0.f;
#pragma unroll
      for (int j = 0; j < QL; ++j) {
        int l = l0 + j;
        float v = (l >= i + 2) ? cbs[j] : 0.f;
        nrm = fmaf(v, v, nrm);
      }
      float xnorm2 = oct_sum(nrm);
      float beta, scl_i;
      if (xnorm2 == 0.f) { beta = alpha; tau_i = 0.f; scl_i = 0.f; }
      else {
        float an = sqrtf(alpha * alpha + xnorm2);
        beta = (alpha >= 0.f) ? -an : an;
        tau_i = (beta - alpha) * rcp_(beta);
        scl_i = rcp_(alpha - beta);
      }
#pragma unroll
      for (int j = 0; j < QL; ++j) {
        int l = l0 + j;
        ul[j] = (l == i + 1) ? 1.f : ((l >= i + 2) ? cbs[j] * scl_i : 0.f);
      }
      if (actR) {
        if (row == i + 1) u_row = 1.f;
        else if (row >= i + 2) u_row = myc * scl_i;
      }
      float s = 0.f;
#pragma unroll
      for (int j = 0; j < QL; ++j) s = fmaf(Ar[j], ul[j], s);
      s = oct_sum(s);
      w_pre = (actR && row >= i + 1) ? tau_i * s : 0.f;
      if (q == 0) S.wwf[row] = w_pre;
      if (row == i + 1 && q == 0) { S.ee[i] = beta; S.taus[i] = tau_i; S.scls[i] = scl_i; }
    } else {
      if (q == 0) S.wwf[row] = 0.f;
    }
    __syncthreads();                                   // A: wwf visible
    if (wact) {
      float wp[QL];
#pragma unroll
      for (int c = 0; c < NC4; ++c) {
        float4 t = ww4[(l0 >> 2) + c];
        wp[4*c] = t.x; wp[4*c+1] = t.y; wp[4*c+2] = t.z; wp[4*c+3] = t.w;
      }
      float p0 = 0.f, p1 = 0.f, p2 = 0.f, p3 = 0.f;
#pragma unroll
      for (int c = 0; c < NC4; ++c) {
        p0 = fmaf(wp[4*c],   ul[4*c],   p0);
        p1 = fmaf(wp[4*c+1], ul[4*c+1], p1);
        p2 = fmaf(wp[4*c+2], ul[4*c+2], p2);
        p3 = fmaf(wp[4*c+3], ul[4*c+3], p3);
      }
      float pu = oct_sum((p0 + p1) + (p2 + p3));
      float halfc = -0.5f * tau_i * pu;
      float w_row = fmaf(halfc, u_row, w_pre);
#pragma unroll
      for (int j = 0; j < QL; ++j) {
        float w_l = fmaf(halfc, ul[j], wp[j]);
        Ar[j] = fmaf(-u_row, w_l, fmaf(-w_row, ul[j], Ar[j]));
      }
      if (row == i + 1) {                              // next pivot column = my row
#pragma unroll
        for (int c = 0; c < NC4; ++c)
          cb4[(l0 >> 2) + c] = make_float4(Ar[4*c], Ar[4*c+1], Ar[4*c+2], Ar[4*c+3]);
      }
    }
    __syncthreads();                                   // B: colbuf visible
  }

  // ---- export diag + packed-lower Householder columns + last off-diag ----
  if (actR) {
    int base = (row * (row - 1)) >> 1;
#pragma unroll
    for (int j = 0; j < QL; ++j) {
      int l = l0 + j;
      if (l == row) S.dd[row] = Ar[j];
      if (l < row)  S.ApkL[base + l] = Ar[j];
      if (row == N - 1 && l == N - 2) S.ee[N - 2] = Ar[j];
    }
  }
  __syncthreads();
  if (tid < N) S.e2s[tid] = (tid >= 1) ? S.ee[tid - 1] * S.ee[tid - 1] : 0.f;

  // ---- Gershgorin bounds + pivmin ----
  if (tid == 0) {
    float lo = 3.4e38f, hi = -3.4e38f, me2 = 0.f;
    for (int ii = 0; ii < N; ++ii) {
      float rad = 0.f;
      if (ii > 0) rad += fabsf(S.ee[ii - 1]);
      if (ii < N - 1) { rad += fabsf(S.ee[ii]); me2 = fmaxf(me2, S.ee[ii] * S.ee[ii]); }
      lo = fminf(lo, S.dd[ii] - rad);
      hi = fmaxf(hi, S.dd[ii] + rad);
    }
    float span = hi - lo;
    S.sca[0] = lo - 0.001f * span - 1e-20f;
    S.sca[1] = hi + 0.001f * span + 1e-20f;
    S.sca[2] = 1.1754944e-38f * fmaxf(1.f, me2);
  }
  __syncthreads();
  const float pivmin = S.sca[2];

  // ---- 33-way multisection: 32 threads per eigenvalue, 6 rounds ----
  {
    const int grp = tid >> 5, gt = tid & 31;
    if (grp < RR) {
      const int krank = N - 1 - grp;
      float lo = S.sca[0], hi = S.sca[1];
      for (int round = 0; round < 6; ++round) {
        float w = (hi - lo) * (1.f / 33.f);
        float sg = fmaf(w, (float)(gt + 1), lo);
        int cnt = 0;
        float qq = S.dd[0] - sg;
        if (qq < 0.f) cnt++;
#pragma unroll 4
        for (int ii = 1; ii < N; ++ii) {
          if (fabsf(qq) < pivmin) qq = -pivmin;
          qq = S.dd[ii] - sg - S.e2s[ii] * rcp_(qq);
          if (qq < 0.f) cnt++;
        }
        float nlo = (cnt <= krank) ? sg : lo;
        float nhi = (cnt >  krank) ? sg : hi;
        nlo = fmaxf(nlo, dppmovf<0xB1>(nlo));  nhi = fminf(nhi, dppmovf<0xB1>(nhi));
        nlo = fmaxf(nlo, dppmovf<0x4E>(nlo));  nhi = fminf(nhi, dppmovf<0x4E>(nhi));
        nlo = fmaxf(nlo, dppmovf<0x124>(nlo)); nhi = fminf(nhi, dppmovf<0x124>(nhi));
        nlo = fmaxf(nlo, dppmovf<0x128>(nlo)); nhi = fminf(nhi, dppmovf<0x128>(nhi));
        nlo = fmaxf(nlo, __shfl_xor(nlo, 16, 32));
        nhi = fminf(nhi, __shfl_xor(nhi, 16, 32));
        lo = fminf(nlo, nhi); hi = fmaxf(nlo, nhi);
      }
      if (gt == 0) S.lam[grp] = 0.5f * (lo + hi) * (1.f + (float)grp * 3e-7f);
    }
  }
  __syncthreads();

  // ---- inverse iteration: float4-packed solver, select pivoting ----
  if (tid < RR) {
    const int j = tid;
    float4* u4 = (float4*)&S.slv[j][0];
    float* vv = &S.vt[j][0];
    const float lj = S.lam[j];
    for (int k = 0; k < N; ++k) vv[k] = 1.f;
    float sc = 1.f;
    for (int itr = 0; itr < 3; ++itr) {
      float d = S.dd[0] - lj;
      float e = S.ee[0];
      float cv = vv[0] * sc;
#pragma unroll 4
      for (int i = 0; i < N - 1; ++i) {
        float bi = S.ee[i];
        float d1 = S.dd[i + 1] - lj;
        float e1 = (i + 1 < N - 1) ? S.ee[i + 1] : 0.f;
        float vnext = vv[i + 1] * sc;
        bool piv = (fabsf(d) >= fabsf(bi));
        float ad = d;
        if (piv && fabsf(ad) < pivmin) ad = (ad >= 0.f ? pivmin : -pivmin);
        float m   = piv ? (bi * rcp_(ad)) : (ad * rcp_(bi));
        float nu0 = piv ? ad : bi;
        float nu1 = piv ? e  : d1;
        float nu2 = piv ? 0.f : e1;
        u4[i] = make_float4(nu0, nu1, nu2, 0.f);
        float nd = piv ? (d1 - m * e) : (e - m * d1);
        float ne = piv ? e1 : (-m * e1);
        vv[i] = piv ? cv : vnext;
        cv = piv ? (vnext - m * cv) : (cv - m * vnext);
        d = nd; e = ne;
      }
      if (fabsf(d) < pivmin) d = (d >= 0.f ? pivmin : -pivmin);
      float vi2 = cv * rcp_(d);
      vv[N - 1] = vi2;
      float mx = fabsf(vi2);
      float4 uN2 = u4[N - 2];
      float vi1 = (vv[N - 2] - uN2.y * vi2) * rcp_(uN2.x);
      vv[N - 2] = vi1;
      mx = fmaxf(mx, fabsf(vi1));
#pragma unroll 4
      for (int i = N - 3; i >= 0; --i) {
        float4 u = u4[i];
        float t = (vv[i] - u.y * vi1 - u.z * vi2) * rcp_(u.x);
        vv[i] = t;
        mx = fmaxf(mx, fabsf(t));
        vi2 = vi1; vi1 = t;
      }
      sc = rcp_(fmaxf(mx, 1e-30f));
    }
    for (int k = 0; k < N; ++k) vv[k] *= sc;   // final normalize (overflow guard)
  }
  __syncthreads();

  // ---- MGS orthonormalization: single wave, DPP reductions ----
  if (wv == 0) {
    const int k1 = lane, k2 = lane + 64;
    for (int j = 0; j < RR; ++j) {
      float vj1 = (k1 < N) ? S.vt[j][k1] : 0.f;
      float vj2 = (k2 < N) ? S.vt[j][k2] : 0.f;
      for (int i2 = 0; i2 < j; ++i2) {
        float a1 = (k1 < N) ? S.vt[i2][k1] : 0.f;
        float a2 = (k2 < N) ? S.vt[i2][k2] : 0.f;
        float p = wave_sum64(vj1 * a1 + vj2 * a2);
        vj1 -= p * a1; vj2 -= p * a2;
      }
      float nn2 = wave_sum64(vj1 * vj1 + vj2 * vj2);
      float inv = rsqrtf(fmaxf(nn2, 1e-33f));
      vj1 *= inv; vj2 *= inv;
      if (k1 < N) S.vt[j][k1] = vj1;
      if (k2 < N) S.vt[j][k2] = vj2;
    }
  }
  __syncthreads();

  // ---- back-transform: v carried in registers; DPP reductions ----
  for (int vec = wv; vec < RR; vec += W) {
    float* v = &S.vt[vec][0];
    const int k1 = lane, k2 = lane + 64;
    float v1 = (k1 < N) ? v[k1] : 0.f;
    float v2 = (k2 < N) ? v[k2] : 0.f;
    for (int h = N - 3; h >= 0; --h) {
      const float sh = S.scls[h];
      float uk1 = 0.f, uk2 = 0.f;
      if (k1 > h && k1 < N)
        uk1 = (k1 == h + 1) ? 1.f : S.ApkL[((k1 * (k1 - 1)) >> 1) + h] * sh;
      if (k2 > h && k2 < N)
        uk2 = (k2 == h + 1) ? 1.f : S.ApkL[((k2 * (k2 - 1)) >> 1) + h] * sh;
      float dp = wave_sum64(uk1 * v1 + uk2 * v2);
      float c = S.taus[h] * dp;
      v1 -= c * uk1; v2 -= c * uk2;
    }
    if (k1 < N) v[k1] = v1;
    if (k2 < N) v[k2] = v2;
  }
  __syncthreads();

  // ---- canonical sign (max-|component| positive) + write F (N x RR) ----
  for (int vec = wv; vec < RR; vec += W) {
    float* v = &S.vt[vec][0];
    float ma = -1.f; int mi = 0x7fffffff;
    for (int k = lane; k < N; k += 64) {
      float a = fabsf(v[k]);
      if (a > ma || (a == ma && k < mi)) { ma = a; mi = k; }
    }
#pragma unroll
    for (int off = 32; off > 0; off >>= 1) {
      float oa = __shfl_down(ma, off, 64);
      int oi = __shfl_down(mi, off, 64);
      if (oa > ma || (oa == ma && oi < mi)) { ma = oa; mi = oi; }
    }
    mi = __shfl(mi, 0, 64);
    float sg = (v[mi] < 0.f) ? -1.f : 1.f;
    for (int k = lane; k < N; k += 64) F[k * RR + vec] = sg * v[k];
  }
}

__global__ __launch_bounds__(1024, 1)
void keigh_init(const float* G1, float* F1, const float* G2, float* F2,
                const float* G3, float* F3) {
  __shared__ ESm S;
  if (blockIdx.x == 0)      eig_body<100, 6, 1024>(S, G1, F1);
  else if (blockIdx.x == 1) eig_body<128, 6, 1024>(S, G2, F2);
  else                      eig_body<64, 6, 1024>(S, G3, F3);
}

template<int N, int RR, int TH>
__global__ __launch_bounds__(TH, 1)
void keigh_one(const float* __restrict__ G, float* __restrict__ F) {
  __shared__ ESm S;
  eig_body<N, RR, TH>(S, G, F);
}

// ---------------- warm-started subspace refinement (sweeps) ----------------
template<int N, int R, int TH, int STEPS>
__global__ __launch_bounds__(TH, 1)
void ksub(const float* __restrict__ G, float* __restrict__ F) {
  __shared__ float Q[R][132];
  __shared__ float Wm[R][132];
  __shared__ float H[R * R];
  __shared__ float U[R * R];
  const int tid = threadIdx.x;
  const int lane = tid & 63, wv = tid >> 6;
  constexpr int WAVES = TH / 64;

  for (int idx = tid; idx < N * R; idx += TH) {
    int k = idx / R, j = idx - k * R;
    Q[j][k] = F[idx];
  }
  __syncthreads();

  for (int step = 0; step < STEPS; ++step) {
    for (int idx = tid; idx < N * R; idx += TH) {
      int k = idx / R, j = idx - k * R;
      const float* gr = G + (long long)k * N;
      float acc = 0.f;
      for (int a = 0; a < N; ++a) acc = fmaf(gr[a], Q[j][a], acc);
      Wm[j][k] = acc;
    }
    __syncthreads();
    if (step < STEPS - 1) {
      if (wv == 0) {                     // MGS rows of Wm -> Q (single wave)
        const int k1 = lane, k2 = lane + 64;
        for (int j = 0; j < R; ++j) {
          float vj1 = (k1 < N) ? Wm[j][k1] : 0.f;
          float vj2 = (k2 < N) ? Wm[j][k2] : 0.f;
          for (int i2 = 0; i2 < j; ++i2) {
            float a1 = (k1 < N) ? Q[i2][k1] : 0.f;
            float a2 = (k2 < N) ? Q[i2][k2] : 0.f;
            float p = wave_sum64(vj1 * a1 + vj2 * a2);
            vj1 -= p * a1; vj2 -= p * a2;
          }
          float nn2 = wave_sum64(vj1 * vj1 + vj2 * vj2);
          float inv = rsqrtf(fmaxf(nn2, 1e-33f));
          vj1 *= inv; vj2 *= inv;
          if (k1 < N) Q[j][k1] = vj1;
          if (k2 < N) Q[j][k2] = vj2;
        }
      }
      __syncthreads();
    }
  }
  // H = Q^T (G Q)
  if (tid < R * R) {
    int i = tid / R, j = tid - i * R;
    float s = 0.f;
    for (int k = 0; k < N; ++k) s = fmaf(Q[i][k], Wm[j][k], s);
    H[i * R + j] = s;
  }
  __syncthreads();
  // Jacobi eigh of H (RxR), sort desc
  if (tid == 0) {
    float A[R][R], V[R][R];
    for (int i = 0; i < R; ++i)
      for (int j = 0; j < R; ++j) { A[i][j] = H[i * R + j]; V[i][j] = (i == j) ? 1.f : 0.f; }
    for (int sw = 0; sw < 8; ++sw)
      for (int p = 0; p < R - 1; ++p)
        for (int qj = p + 1; qj < R; ++qj) {
          float apq = A[p][qj];
          if (fabsf(apq) < 1e-12f) continue;
          float theta = 0.5f * (A[qj][qj] - A[p][p]) / apq;
          float t = ((theta >= 0.f) ? 1.f : -1.f) / (fabsf(theta) + sqrtf(theta * theta + 1.f));
          float c = rsqrtf(t * t + 1.f);
          float s = t * c;
          for (int k2 = 0; k2 < R; ++k2) {
            float akp = A[k2][p], akq = A[k2][qj];
            A[k2][p] = c * akp - s * akq;
            A[k2][qj] = s * akp + c * akq;
          }
          for (int k2 = 0; k2 < R; ++k2) {
            float apk = A[p][k2], aqk = A[qj][k2];
            A[p][k2] = c * apk - s * aqk;
            A[qj][k2] = s * apk + c * aqk;
          }
          for (int k2 = 0; k2 < R; ++k2) {
            float vkp = V[k2][p], vkq = V[k2][qj];
            V[k2][p] = c * vkp - s * vkq;
            V[k2][qj] = s * vkp + c * vkq;
          }
        }
    int ord[R];
    for (int i = 0; i < R; ++i) ord[i] = i;
    for (int i = 0; i < R; ++i) {
      int mi = i;
      for (int j = i + 1; j < R; ++j)
        if (A[ord[j]][ord[j]] > A[ord[mi]][ord[mi]]) mi = j;
      int t2 = ord[i]; ord[i] = ord[mi]; ord[mi] = t2;
    }
    for (int i = 0; i < R; ++i)
      for (int j = 0; j < R; ++j) U[j * R + i] = V[j][ord[i]];
  }
  __syncthreads();
  for (int idx = tid; idx < N * R; idx += TH) {
    int k = idx / R, i = idx - k * R;
    float s = 0.f;
#pragma unroll
    for (int j = 0; j < R; ++j) s = fmaf(U[j * R + i], Q[j][k], s);
    Wm[i][k] = s;
  }
  __syncthreads();
  for (int vec = wv; vec < R; vec += WAVES) {
    float* v = &Wm[vec][0];
    float ma = -1.f; int mi = 0x7fffffff;
    for (int k = lane; k < N; k += 64) {
      float a = fabsf(v[k]);
      if (a > ma || (a == ma && k < mi)) { ma = a; mi = k; }
    }
#pragma unroll
    for (int off = 32; off > 0; off >>= 1) {
      float oa = __shfl_down(ma, off, 64);
      int oi = __shfl_down(mi, off, 64);
      if (oa > ma || (oa == ma && oi < mi)) { ma = oa; mi = oi; }
    }
    mi = __shfl(mi, 0, 64);
    float sg = (v[mi] < 0.f) ? -1.f : 1.f;
    for (int k = lane; k < N; k += 64) F[k * R + vec] = sg * v[k];
  }
}

// ---------------------------------------------------------------------------
extern "C" void kernel_launch(void* const* d_in, const int* in_sizes, int n_in,
                              void* d_out, int out_size, void* d_ws, size_t ws_size,
                              hipStream_t stream) {
  (void)in_sizes; (void)n_in; (void)out_size; (void)ws_size;
  const float* x  = (const float*)d_in[0];
  const float* cw = (const float*)d_in[1];
  const float* cb = (const float*)d_in[2];
  float* out = (float*)d_out;
  float* ws  = (float*)d_ws;

  float* T    = ws + OFF_T;
  float* TC   = ws + OFF_TC;
  float* TB   = ws + OFF_TB;
  float* PART = ws + OFF_PART;
  float* P2   = ws + OFF_P2;
  float* TD0a = ws + OFF_TD0a;
  float* TD0b = ws + OFF_TD0b;
  float* TD   = ws + OFF_TD;
  float* G0   = ws + OFF_G0;
  float* G1   = ws + OFF_G1;
  float* G2   = ws + OFF_G2;
  float* G3   = ws + OFF_G3;
  float* F0   = ws + OFF_F0;
  float* F1   = ws + OFF_F1;
  float* F2   = ws + OFF_F2;
  float* F3   = ws + OFF_F3;

  kconv<<<(26214400 + 255) / 256, 256, 0, stream>>>(x, cw, cb, T);

  // ---- HOSVD init: 3 grams (F0's init was dead: sweep-0 recomputes F0) ----
  kgram_big<100, 8192, false><<<640, 256, 0, stream>>>(T, PART, 32);
  kreduce1<<<RED_K * 40, 256, 0, stream>>>(PART, P2, 10000, 640);
  kreduce2<<<40, 256, 0, stream>>>(P2, G1, 10000);
  kgram_big<128, 64, false><<<400, 256, 0, stream>>>(T, PART, 3200);
  kreduce1<<<RED_K * 64, 256, 0, stream>>>(PART, P2, 16384, 400);
  kreduce2<<<64, 256, 0, stream>>>(P2, G2, 16384);
  kgram_big<64, 1, true><<<1536, 256, 0, stream>>>(T, PART, 409600);
  kreduce1<<<RED_K * 16, 256, 0, stream>>>(PART, P2, 4096, 1536);
  kreduce2<<<16, 256, 0, stream>>>(P2, G3, 4096);

  keigh_init<<<3, 1024, 0, stream>>>(G1, F1, G2, F2, G3, F3);

  // ---- HOOI sweeps: 4 sweeps (fixed point converged by sweep 3);
  //      interiors STEPS=3, final sweep STEPS=4 (accuracy anchor) ----
  for (int sweep = 0; sweep < 4; ++sweep) {
    const bool last = (sweep == 3);
    // mode 0
    kcontract<6, 8192><<<1024, 256, 0, stream>>>(T, F1, TB, 32, 100);
    kcontract<6, 64><<<48, 256, 0, stream>>>(TB, F2, TD0a, 192, 128);
    kcontract<6, 1><<<5, 256, 0, stream>>>(TD0a, F3, TD0b, 1152, 64);
    kgram_small<<<4, 256, 0, stream>>>(TD0b, G0, 1, 32, 216);
    if (sweep == 0)  keigh_one<32, 8, 256><<<1, 256, 0, stream>>>(G0, F0);
    else if (last)   ksub<32, 8, 256, 4><<<1, 256, 0, stream>>>(G0, F0);
    else             ksub<32, 8, 256, 3><<<1, 256, 0, stream>>>(G0, F0);
    // TC = T x0 F0 (reused by modes 1,2,3 and the final core)
    kcontract<8, 819200><<<3200, 256, 0, stream>>>(T, F0, TC, 1, 32);
    // mode 1
    kcontract<6, 64><<<200, 256, 0, stream>>>(TC, F2, TB, 800, 128);
    kcontract<6, 1><<<19, 256, 0, stream>>>(TB, F3, TD, 4800, 64);
    kgram_small<<<40, 256, 0, stream>>>(TD, G0, 8, 100, 36);
    if (last) ksub<100, 6, 1024, 4><<<1, 1024, 0, stream>>>(G0, F1);
    else      ksub<100, 6, 1024, 3><<<1, 1024, 0, stream>>>(G0, F1);
    // mode 2 (TB = TC x1 F1 also reused by mode 3 AND the final core)
    kcontract<6, 8192><<<256, 256, 0, stream>>>(TC, F1, TB, 8, 100);
    kcontract<6, 1><<<24, 256, 0, stream>>>(TB, F3, TD, 6144, 64);
    kgram_small<<<64, 256, 0, stream>>>(TD, G0, 48, 128, 6);
    if (last) ksub<128, 6, 1024, 4><<<1, 1024, 0, stream>>>(G0, F2);
    else      ksub<128, 6, 1024, 3><<<1, 1024, 0, stream>>>(G0, F2);
    // mode 3 (reuses TB; its TD = TB x2 F2 is ALSO the final core's TD)
    kcontract<6, 64><<<12, 256, 0, stream>>>(TB, F2, TD, 48, 128);
    kgram_small<<<16, 256, 0, stream>>>(TD, G0, 288, 64, 1);
    if (last) ksub<64, 6, 512, 4><<<1, 512, 0, stream>>>(G0, F3);
    else      ksub<64, 6, 512, 3><<<1, 512, 0, stream>>>(G0, F3);
  }

  // ---- core: TB (= TC x1 F1) and TD (= TB x2 F2) already hold last-sweep
  //      mode-2/3 outputs with the final F1/F2 -> only the F3 contraction ----
  kcontract<6, 1><<<2, 256, 0, stream>>>(TD, F3, out, 288, 64);
}

// Round 17
// 3009.360 us; speedup vs baseline: 1.2242x; 1.2242x over previous
//
#include <hip/hip_runtime.h>
#include <math.h>

// ---------------------------------------------------------------------------
// TensorProcessor: conv3d(1,3,1)+bias+relu -> Tucker-HOOI core (8,6,6,6)
// Round 22: combine r20+r21 winners. 4 HOOI sweeps (r21 proved accuracy-safe:
// absmax 12.22) with STEPS=2 interiors (r20's proven step count). Hedges:
// sweep 0 STEPS=3 (worst warm starts), final sweep STEPS=4 anchor. ksub's
// serial 6x6 Jacobi 8->5 sweeps (H near-diagonal when warm; quadratic
// convergence). Exact solvers untouched. Everything else r20-identical:
// exact 3-block keigh_init, exact sweep-0 F0, dataflow-trimmed tails,
// transposed-tile grams, 2-stage reduce.
// ---------------------------------------------------------------------------

// ws layout (float offsets)
constexpr long long OFF_T   = 0LL;                 // 26,214,400
constexpr long long OFF_TC  = 26214400LL;          // 6,553,600
constexpr long long OFF_TB  = 32768000LL;          // 1,572,864
constexpr long long OFF_PART= OFF_TC;              // <=6,553,600 (init only)
constexpr long long OFF_P2  = OFF_TB;              // <=524,288 (init only)
constexpr long long OFF_TD0a= OFF_TC;              // mode0 (32,6,6,64)=73,728
constexpr long long OFF_TD0b= OFF_TC + 131072;     // mode0 (32,6,6,6)=6,912
constexpr long long OFF_TD  = OFF_TB + 1000000LL;  // sweep small tensors
constexpr long long OFF_G0  = OFF_TB + 1400000LL;  // 1,024
constexpr long long OFF_G1  = OFF_G0 + 1024;       // 10,000
constexpr long long OFF_G2  = OFF_G1 + 10000;      // 16,384
constexpr long long OFF_G3  = OFF_G2 + 16384;      // 4,096
constexpr long long OFF_F0  = 34340864LL;          // 256
constexpr long long OFF_F1  = OFF_F0 + 256;        // 600
constexpr long long OFF_F2  = OFF_F1 + 600;        // 768
constexpr long long OFF_F3  = OFF_F2 + 768;        // 384

__device__ __forceinline__ float rcp_(float x) { return __builtin_amdgcn_rcpf(x); }

template<int CTRL>
__device__ __forceinline__ float dppmovf(float v) {
  return __int_as_float(__builtin_amdgcn_update_dpp(
      0, __float_as_int(v), CTRL, 0xF, 0xF, true));
}
// sum over 8 consecutive lanes, all-DPP (identical in all 8 lanes)
__device__ __forceinline__ float oct_sum(float v) {
  v += dppmovf<0xB1>(v);    // quad_perm xor1
  v += dppmovf<0x4E>(v);    // quad_perm xor2
  v += dppmovf<0x141>(v);   // row_half_mirror
  return v;
}
// full 64-lane sum, result in all lanes
__device__ __forceinline__ float wave_sum64(float v) {
  v += dppmovf<0xB1>(v);
  v += dppmovf<0x4E>(v);
  v += dppmovf<0x124>(v);   // row_ror:4
  v += dppmovf<0x128>(v);   // row_ror:8
  v += __shfl_xor(v, 16, 64);
  v += __shfl_xor(v, 32, 64);
  return v;
}

// ---------------- conv + relu ----------------
__global__ void kconv(const float* __restrict__ x, const float* __restrict__ cw,
                      const float* __restrict__ cb, float* __restrict__ t) {
  int idx = blockIdx.x * blockDim.x + threadIdx.x;
  if (idx >= 26214400) return;
  int w  = idx & 63;
  int h  = (idx >> 6) & 127;
  int d  = (idx >> 13) % 100;
  int o  = idx / 819200;
  float acc = cb[o];
#pragma unroll
  for (int i = 0; i < 4; ++i) {
    const float* xi = x + (((long long)i * 100 + d) * 130 + h) * 64 + w;
#pragma unroll
    for (int kh = 0; kh < 3; ++kh)
      acc = fmaf(cw[(o * 4 + i) * 3 + kh], xi[kh * 64], acc);
  }
  t[idx] = fmaxf(acc, 0.f);
}

// ---------------- big gram (init HOSVD): G = X X^T over fibers ----------------
template<int D, long long QQ, bool TRANS>
__global__ void kgram_big(const float* __restrict__ T, float* __restrict__ part,
                          int P) {
  constexpr int C = 64;
  constexpr int SUB = (D + 63) / 64;
  constexpr int DP = SUB * 64;
  constexpr int STR = DP + 4;                // 16B-aligned float stride
  __shared__ float tile[C * STR];
  const int tid = threadIdx.x;               // 256
  const int ta = tid >> 4, tb = tid & 15;
  float acc[SUB][SUB][4][4];
#pragma unroll
  for (int a = 0; a < SUB; ++a)
#pragma unroll
    for (int b = 0; b < SUB; ++b)
#pragma unroll
      for (int i = 0; i < 4; ++i)
#pragma unroll
        for (int j = 0; j < 4; ++j) acc[a][b][i][j] = 0.f;

  const long long nfib = (long long)P * QQ;
  const int nchunk = (int)(nfib / C);
  for (int ch = blockIdx.x; ch < nchunk; ch += gridDim.x) {
    const long long base = (long long)ch * C;
    __syncthreads();
    if (TRANS) {
      for (int e = tid; e < D * C; e += 256) {
        int a = e & 63, cc = e >> 6;         // a fast -> global coalesced
        tile[cc * STR + a] = T[base * D + e];
      }
    } else {
      for (int e = tid; e < DP * C; e += 256) {
        int cc = e & 63, a = e >> 6;         // cc fast -> global coalesced
        float v = 0.f;
        if (a < D) {
          long long f = base + cc;
          long long p = f / QQ, q = f - p * QQ;   // compile-time QQ
          v = T[(p * D + a) * QQ + q];
        }
        tile[cc * STR + a] = v;
      }
    }
    __syncthreads();
    for (int cc = 0; cc < C; ++cc) {
      const float* tr = &tile[cc * STR];
      float4 av[SUB], bv[SUB];
#pragma unroll
      for (int si = 0; si < SUB; ++si) av[si] = *(const float4*)&tr[si * 64 + ta * 4];
#pragma unroll
      for (int sj = 0; sj < SUB; ++sj) bv[sj] = *(const float4*)&tr[sj * 64 + tb * 4];
#pragma unroll
      for (int si = 0; si < SUB; ++si)
#pragma unroll
        for (int sj = 0; sj < SUB; ++sj) {
          const float a0 = av[si].x, a1 = av[si].y, a2 = av[si].z, a3 = av[si].w;
          const float b0 = bv[sj].x, b1 = bv[sj].y, b2 = bv[sj].z, b3 = bv[sj].w;
          acc[si][sj][0][0] = fmaf(a0, b0, acc[si][sj][0][0]);
          acc[si][sj][0][1] = fmaf(a0, b1, acc[si][sj][0][1]);
          acc[si][sj][0][2] = fmaf(a0, b2, acc[si][sj][0][2]);
          acc[si][sj][0][3] = fmaf(a0, b3, acc[si][sj][0][3]);
          acc[si][sj][1][0] = fmaf(a1, b0, acc[si][sj][1][0]);
          acc[si][sj][1][1] = fmaf(a1, b1, acc[si][sj][1][1]);
          acc[si][sj][1][2] = fmaf(a1, b2, acc[si][sj][1][2]);
          acc[si][sj][1][3] = fmaf(a1, b3, acc[si][sj][1][3]);
          acc[si][sj][2][0] = fmaf(a2, b0, acc[si][sj][2][0]);
          acc[si][sj][2][1] = fmaf(a2, b1, acc[si][sj][2][1]);
          acc[si][sj][2][2] = fmaf(a2, b2, acc[si][sj][2][2]);
          acc[si][sj][2][3] = fmaf(a2, b3, acc[si][sj][2][3]);
          acc[si][sj][3][0] = fmaf(a3, b0, acc[si][sj][3][0]);
          acc[si][sj][3][1] = fmaf(a3, b1, acc[si][sj][3][1]);
          acc[si][sj][3][2] = fmaf(a3, b2, acc[si][sj][3][2]);
          acc[si][sj][3][3] = fmaf(a3, b3, acc[si][sj][3][3]);
        }
    }
  }
  float* pb = part + (long long)blockIdx.x * D * D;
  for (int si = 0; si < SUB; ++si)
    for (int i = 0; i < 4; ++i) {
      int a = si * 64 + ta * 4 + i;
      if (a >= D) continue;
      for (int sj = 0; sj < SUB; ++sj)
        for (int j = 0; j < 4; ++j) {
          int b = sj * 64 + tb * 4 + j;
          if (b >= D) continue;
          pb[a * D + b] = acc[si][sj][i][j];
        }
    }
}

// two-stage reduce: stage1 sums a 1/K slice of b per (k,i); stage2 sums K.
#define RED_K 32
__global__ void kreduce1(const float* __restrict__ part, float* __restrict__ part2,
                         int DD, int nblk) {
  int nb = (DD + 255) >> 8;
  int k = blockIdx.x / nb;
  int i = (blockIdx.x - k * nb) * 256 + threadIdx.x;
  if (i >= DD) return;
  int b0 = (int)((long long)k * nblk / RED_K);
  int b1 = (int)((long long)(k + 1) * nblk / RED_K);
  float s = 0.f;
  for (int b = b0; b < b1; ++b) s += part[(long long)b * DD + i];
  part2[(long long)k * DD + i] = s;
}
__global__ void kreduce2(const float* __restrict__ part2, float* __restrict__ G,
                         int DD) {
  int i = blockIdx.x * 256 + threadIdx.x;
  if (i >= DD) return;
  float s = 0.f;
#pragma unroll 8
  for (int k = 0; k < RED_K; ++k) s += part2[(long long)k * DD + i];
  G[i] = s;
}

// ---------------- small gram (projected Y) ----------------
__global__ void kgram_small(const float* __restrict__ Y, float* __restrict__ G,
                            int P, int d, int Q) {
  int pair = blockIdx.x * blockDim.x + threadIdx.x;
  if (pair >= d * d) return;
  int a = pair / d, b = pair % d;
  float s = 0.f;
  for (int p = 0; p < P; ++p) {
    const float* ya = Y + ((long long)p * d + a) * Q;
    const float* yb = Y + ((long long)p * d + b) * Q;
    for (int q = 0; q < Q; ++q) s = fmaf(ya[q], yb[q], s);
  }
  G[pair] = s;
}

// ---------------- mode contraction: out[p,j,q] = sum_a F[a,j] in[p,a,q] ----------------
template<int R, long long QV>
__global__ void kcontract(const float* __restrict__ in, const float* __restrict__ F,
                          float* __restrict__ out, int P, int d) {
  long long total = (long long)P * QV;
  long long idx = (long long)blockIdx.x * blockDim.x + threadIdx.x;
  if (idx >= total) return;
  long long p = idx / QV, q = idx - p * QV;
  float acc[R];
#pragma unroll
  for (int j = 0; j < R; ++j) acc[j] = 0.f;
  const float* ip = in + (p * d) * QV + q;
  for (int a = 0; a < d; ++a) {
    float v = ip[(long long)a * QV];
#pragma unroll
    for (int j = 0; j < R; ++j) acc[j] = fmaf(F[a * R + j], v, acc[j]);
  }
  float* op = out + (p * R) * QV + q;
#pragma unroll
  for (int j = 0; j < R; ++j) op[(long long)j * QV] = acc[j];
}

// ---------------- eigh: top-r eigenvectors of symmetric G (n<=128) ----------------
struct __align__(16) ESm {
  float ApkL[8256];              // packed-lower Householder columns (export)
  float colbuf[128];             // current pivot column (16B-aligned)
  float wwf[128];                // w_pre vector
  float slv[8][516];             // invit solver: float4 {u0,u1,u2,-} per i
  float dd[128], ee[128], e2s[128], taus[128], scls[128];
  float vt[8][132];
  float lam[8];
  float sca[4];
};

template<int N, int RR, int TH>
__device__ void eig_body(ESm& S, const float* __restrict__ G, float* __restrict__ F) {
  constexpr int NP  = (N <= 32) ? 32 : ((N <= 64) ? 64 : 128);
  constexpr int QL  = NP / 8;          // floats per thread segment (4/8/16)
  constexpr int NC4 = QL / 4;          // float4 chunks per segment (1/2/4)
  constexpr int W   = TH / 64;         // waves in block
  const int tid  = threadIdx.x;
  const int lane = tid & 63, wv = tid >> 6;
  const int q    = tid & 7;            // 8 adjacent lanes share a row
  const int row  = tid >> 3;
  const bool actR = (row < N);
  const int l0 = q * QL;
  const int wrow0 = wv << 3;           // 8 rows per wave

  float4* cb4 = (float4*)S.colbuf;
  float4* ww4 = (float4*)S.wwf;

  // ---- load: thread (row,q) owns A[row][l0 .. l0+QL) in VGPRs ----
  float Ar[QL];
#pragma unroll
  for (int j = 0; j < QL; ++j) Ar[j] = 0.f;
  if (actR) {
#pragma unroll
    for (int j = 0; j < QL; ++j) { int l = l0 + j; if (l < N) Ar[j] = G[row * N + l]; }
  }
  if (row == 0) {                      // colbuf <- column 0 = row 0 (pads exact 0)
#pragma unroll
    for (int c = 0; c < NC4; ++c)
      cb4[(l0 >> 2) + c] = make_float4(Ar[4*c], Ar[4*c+1], Ar[4*c+2], Ar[4*c+3]);
  }
  __syncthreads();

  // ---- Householder tridiagonalization (LAPACK slarfg conventions) ----
  for (int i = 0; i <= N - 3; ++i) {
    const bool wact = (wrow0 + 7 >= i + 1) && (wrow0 <= N - 1);
    float tau_i = 0.f, u_row = 0.f, w_pre = 0.f;
    float ul[QL];
    if (wact) {
      float cbs[QL];
#pragma unroll
      for (int c = 0; c < NC4; ++c) {
        float4 t = cb4[(l0 >> 2) + c];
        cbs[4*c] = t.x; cbs[4*c+1] = t.y; cbs[4*c+2] = t.z; cbs[4*c+3] = t.w;
      }
      float alpha = S.colbuf[i + 1];
      float myc   = S.colbuf[row];

      float nrm = 0.f;
#pragma unroll
      for (int j = 0; j < QL; ++j) {
        int l = l0 + j;
        float v = (l >= i + 2) ? cbs[j] : 0.f;
        nrm = fmaf(v, v, nrm);
      }
      float xnorm2 = oct_sum(nrm);
      float beta, scl_i;
      if (xnorm2 == 0.f) { beta = alpha; tau_i = 0.f; scl_i = 0.f; }
      else {
        float an = sqrtf(alpha * alpha + xnorm2);
        beta = (alpha >= 0.f) ? -an : an;
        tau_i = (beta - alpha) * rcp_(beta);
        scl_i = rcp_(alpha - beta);
      }
#pragma unroll
      for (int j = 0; j < QL; ++j) {
        int l = l0 + j;
        ul[j] = (l == i + 1) ? 1.f : ((l >= i + 2) ? cbs[j] * scl_i : 0.f);
      }
      if (actR) {
        if (row == i + 1) u_row = 1.f;
        else if (row >= i + 2) u_row = myc * scl_i;
      }
      float s = 0.f;
#pragma unroll
      for (int j = 0; j < QL; ++j) s = fmaf(Ar[j], ul[j], s);
      s = oct_sum(s);
      w_pre = (actR && row >= i + 1) ? tau_i * s : 0.f;
      if (q == 0) S.wwf[row] = w_pre;
      if (row == i + 1 && q == 0) { S.ee[i] = beta; S.taus[i] = tau_i; S.scls[i] = scl_i; }
    } else {
      if (q == 0) S.wwf[row] = 0.f;
    }
    __syncthreads();                                   // A: wwf visible
    if (wact) {
      float wp[QL];
#pragma unroll
      for (int c = 0; c < NC4; ++c) {
        float4 t = ww4[(l0 >> 2) + c];
        wp[4*c] = t.x; wp[4*c+1] = t.y; wp[4*c+2] = t.z; wp[4*c+3] = t.w;
      }
      float p0 = 0.f, p1 = 0.f, p2 = 0.f, p3 = 0.f;
#pragma unroll
      for (int c = 0; c < NC4; ++c) {
        p0 = fmaf(wp[4*c],   ul[4*c],   p0);
        p1 = fmaf(wp[4*c+1], ul[4*c+1], p1);
        p2 = fmaf(wp[4*c+2], ul[4*c+2], p2);
        p3 = fmaf(wp[4*c+3], ul[4*c+3], p3);
      }
      float pu = oct_sum((p0 + p1) + (p2 + p3));
      float halfc = -0.5f * tau_i * pu;
      float w_row = fmaf(halfc, u_row, w_pre);
#pragma unroll
      for (int j = 0; j < QL; ++j) {
        float w_l = fmaf(halfc, ul[j], wp[j]);
        Ar[j] = fmaf(-u_row, w_l, fmaf(-w_row, ul[j], Ar[j]));
      }
      if (row == i + 1) {                              // next pivot column = my row
#pragma unroll
        for (int c = 0; c < NC4; ++c)
          cb4[(l0 >> 2) + c] = make_float4(Ar[4*c], Ar[4*c+1], Ar[4*c+2], Ar[4*c+3]);
      }
    }
    __syncthreads();                                   // B: colbuf visible
  }

  // ---- export diag + packed-lower Householder columns + last off-diag ----
  if (actR) {
    int base = (row * (row - 1)) >> 1;
#pragma unroll
    for (int j = 0; j < QL; ++j) {
      int l = l0 + j;
      if (l == row) S.dd[row] = Ar[j];
      if (l < row)  S.ApkL[base + l] = Ar[j];
      if (row == N - 1 && l == N - 2) S.ee[N - 2] = Ar[j];
    }
  }
  __syncthreads();
  if (tid < N) S.e2s[tid] = (tid >= 1) ? S.ee[tid - 1] * S.ee[tid - 1] : 0.f;

  // ---- Gershgorin bounds + pivmin ----
  if (tid == 0) {
    float lo = 3.4e38f, hi = -3.4e38f, me2 = 0.f;
    for (int ii = 0; ii < N; ++ii) {
      float rad = 0.f;
      if (ii > 0) rad += fabsf(S.ee[ii - 1]);
      if (ii < N - 1) { rad += fabsf(S.ee[ii]); me2 = fmaxf(me2, S.ee[ii] * S.ee[ii]); }
      lo = fminf(lo, S.dd[ii] - rad);
      hi = fmaxf(hi, S.dd[ii] + rad);
    }
    float span = hi - lo;
    S.sca[0] = lo - 0.001f * span - 1e-20f;
    S.sca[1] = hi + 0.001f * span + 1e-20f;
    S.sca[2] = 1.1754944e-38f * fmaxf(1.f, me2);
  }
  __syncthreads();
  const float pivmin = S.sca[2];

  // ---- 33-way multisection: 32 threads per eigenvalue, 6 rounds ----
  {
    const int grp = tid >> 5, gt = tid & 31;
    if (grp < RR) {
      const int krank = N - 1 - grp;
      float lo = S.sca[0], hi = S.sca[1];
      for (int round = 0; round < 6; ++round) {
        float w = (hi - lo) * (1.f / 33.f);
        float sg = fmaf(w, (float)(gt + 1), lo);
        int cnt = 0;
        float qq = S.dd[0] - sg;
        if (qq < 0.f) cnt++;
#pragma unroll 4
        for (int ii = 1; ii < N; ++ii) {
          if (fabsf(qq) < pivmin) qq = -pivmin;
          qq = S.dd[ii] - sg - S.e2s[ii] * rcp_(qq);
          if (qq < 0.f) cnt++;
        }
        float nlo = (cnt <= krank) ? sg : lo;
        float nhi = (cnt >  krank) ? sg : hi;
        nlo = fmaxf(nlo, dppmovf<0xB1>(nlo));  nhi = fminf(nhi, dppmovf<0xB1>(nhi));
        nlo = fmaxf(nlo, dppmovf<0x4E>(nlo));  nhi = fminf(nhi, dppmovf<0x4E>(nhi));
        nlo = fmaxf(nlo, dppmovf<0x124>(nlo)); nhi = fminf(nhi, dppmovf<0x124>(nhi));
        nlo = fmaxf(nlo, dppmovf<0x128>(nlo)); nhi = fminf(nhi, dppmovf<0x128>(nhi));
        nlo = fmaxf(nlo, __shfl_xor(nlo, 16, 32));
        nhi = fminf(nhi, __shfl_xor(nhi, 16, 32));
        lo = fminf(nlo, nhi); hi = fmaxf(nlo, nhi);
      }
      if (gt == 0) S.lam[grp] = 0.5f * (lo + hi) * (1.f + (float)grp * 3e-7f);
    }
  }
  __syncthreads();

  // ---- inverse iteration: float4-packed solver, select pivoting ----
  if (tid < RR) {
    const int j = tid;
    float4* u4 = (float4*)&S.slv[j][0];
    float* vv = &S.vt[j][0];
    const float lj = S.lam[j];
    for (int k = 0; k < N; ++k) vv[k] = 1.f;
    float sc = 1.f;
    for (int itr = 0; itr < 3; ++itr) {
      float d = S.dd[0] - lj;
      float e = S.ee[0];
      float cv = vv[0] * sc;
#pragma unroll 4
      for (int i = 0; i < N - 1; ++i) {
        float bi = S.ee[i];
        float d1 = S.dd[i + 1] - lj;
        float e1 = (i + 1 < N - 1) ? S.ee[i + 1] : 0.f;
        float vnext = vv[i + 1] * sc;
        bool piv = (fabsf(d) >= fabsf(bi));
        float ad = d;
        if (piv && fabsf(ad) < pivmin) ad = (ad >= 0.f ? pivmin : -pivmin);
        float m   = piv ? (bi * rcp_(ad)) : (ad * rcp_(bi));
        float nu0 = piv ? ad : bi;
        float nu1 = piv ? e  : d1;
        float nu2 = piv ? 0.f : e1;
        u4[i] = make_float4(nu0, nu1, nu2, 0.f);
        float nd = piv ? (d1 - m * e) : (e - m * d1);
        float ne = piv ? e1 : (-m * e1);
        vv[i] = piv ? cv : vnext;
        cv = piv ? (vnext - m * cv) : (cv - m * vnext);
        d = nd; e = ne;
      }
      if (fabsf(d) < pivmin) d = (d >= 0.f ? pivmin : -pivmin);
      float vi2 = cv * rcp_(d);
      vv[N - 1] = vi2;
      float mx = fabsf(vi2);
      float4 uN2 = u4[N - 2];
      float vi1 = (vv[N - 2] - uN2.y * vi2) * rcp_(uN2.x);
      vv[N - 2] = vi1;
      mx = fmaxf(mx, fabsf(vi1));
#pragma unroll 4
      for (int i = N - 3; i >= 0; --i) {
        float4 u = u4[i];
        float t = (vv[i] - u.y * vi1 - u.z * vi2) * rcp_(u.x);
        vv[i] = t;
        mx = fmaxf(mx, fabsf(t));
        vi2 = vi1; vi1 = t;
      }
      sc = rcp_(fmaxf(mx, 1e-30f));
    }
    for (int k = 0; k < N; ++k) vv[k] *= sc;   // final normalize (overflow guard)
  }
  __syncthreads();

  // ---- MGS orthonormalization: single wave, DPP reductions ----
  if (wv == 0) {
    const int k1 = lane, k2 = lane + 64;
    for (int j = 0; j < RR; ++j) {
      float vj1 = (k1 < N) ? S.vt[j][k1] : 0.f;
      float vj2 = (k2 < N) ? S.vt[j][k2] : 0.f;
      for (int i2 = 0; i2 < j; ++i2) {
        float a1 = (k1 < N) ? S.vt[i2][k1] : 0.f;
        float a2 = (k2 < N) ? S.vt[i2][k2] : 0.f;
        float p = wave_sum64(vj1 * a1 + vj2 * a2);
        vj1 -= p * a1; vj2 -= p * a2;
      }
      float nn2 = wave_sum64(vj1 * vj1 + vj2 * vj2);
      float inv = rsqrtf(fmaxf(nn2, 1e-33f));
      vj1 *= inv; vj2 *= inv;
      if (k1 < N) S.vt[j][k1] = vj1;
      if (k2 < N) S.vt[j][k2] = vj2;
    }
  }
  __syncthreads();

  // ---- back-transform: v carried in registers; DPP reductions ----
  for (int vec = wv; vec < RR; vec += W) {
    float* v = &S.vt[vec][0];
    const int k1 = lane, k2 = lane + 64;
    float v1 = (k1 < N) ? v[k1] : 0.f;
    float v2 = (k2 < N) ? v[k2] : 0.f;
    for (int h = N - 3; h >= 0; --h) {
      const float sh = S.scls[h];
      float uk1 = 0.f, uk2 = 0.f;
      if (k1 > h && k1 < N)
        uk1 = (k1 == h + 1) ? 1.f : S.ApkL[((k1 * (k1 - 1)) >> 1) + h] * sh;
      if (k2 > h && k2 < N)
        uk2 = (k2 == h + 1) ? 1.f : S.ApkL[((k2 * (k2 - 1)) >> 1) + h] * sh;
      float dp = wave_sum64(uk1 * v1 + uk2 * v2);
      float c = S.taus[h] * dp;
      v1 -= c * uk1; v2 -= c * uk2;
    }
    if (k1 < N) v[k1] = v1;
    if (k2 < N) v[k2] = v2;
  }
  __syncthreads();

  // ---- canonical sign (max-|component| positive) + write F (N x RR) ----
  for (int vec = wv; vec < RR; vec += W) {
    float* v = &S.vt[vec][0];
    float ma = -1.f; int mi = 0x7fffffff;
    for (int k = lane; k < N; k += 64) {
      float a = fabsf(v[k]);
      if (a > ma || (a == ma && k < mi)) { ma = a; mi = k; }
    }
#pragma unroll
    for (int off = 32; off > 0; off >>= 1) {
      float oa = __shfl_down(ma, off, 64);
      int oi = __shfl_down(mi, off, 64);
      if (oa > ma || (oa == ma && oi < mi)) { ma = oa; mi = oi; }
    }
    mi = __shfl(mi, 0, 64);
    float sg = (v[mi] < 0.f) ? -1.f : 1.f;
    for (int k = lane; k < N; k += 64) F[k * RR + vec] = sg * v[k];
  }
}

__global__ __launch_bounds__(1024, 1)
void keigh_init(const float* G1, float* F1, const float* G2, float* F2,
                const float* G3, float* F3) {
  __shared__ ESm S;
  if (blockIdx.x == 0)      eig_body<100, 6, 1024>(S, G1, F1);
  else if (blockIdx.x == 1) eig_body<128, 6, 1024>(S, G2, F2);
  else                      eig_body<64, 6, 1024>(S, G3, F3);
}

template<int N, int RR, int TH>
__global__ __launch_bounds__(TH, 1)
void keigh_one(const float* __restrict__ G, float* __restrict__ F) {
  __shared__ ESm S;
  eig_body<N, RR, TH>(S, G, F);
}

// ---------------- warm-started subspace refinement (sweeps) ----------------
template<int N, int R, int TH, int STEPS>
__global__ __launch_bounds__(TH, 1)
void ksub(const float* __restrict__ G, float* __restrict__ F) {
  __shared__ float Q[R][132];
  __shared__ float Wm[R][132];
  __shared__ float H[R * R];
  __shared__ float U[R * R];
  const int tid = threadIdx.x;
  const int lane = tid & 63, wv = tid >> 6;
  constexpr int WAVES = TH / 64;

  for (int idx = tid; idx < N * R; idx += TH) {
    int k = idx / R, j = idx - k * R;
    Q[j][k] = F[idx];
  }
  __syncthreads();

  for (int step = 0; step < STEPS; ++step) {
    for (int idx = tid; idx < N * R; idx += TH) {
      int k = idx / R, j = idx - k * R;
      const float* gr = G + (long long)k * N;
      float acc = 0.f;
      for (int a = 0; a < N; ++a) acc = fmaf(gr[a], Q[j][a], acc);
      Wm[j][k] = acc;
    }
    __syncthreads();
    if (step < STEPS - 1) {
      if (wv == 0) {                     // MGS rows of Wm -> Q (single wave)
        const int k1 = lane, k2 = lane + 64;
        for (int j = 0; j < R; ++j) {
          float vj1 = (k1 < N) ? Wm[j][k1] : 0.f;
          float vj2 = (k2 < N) ? Wm[j][k2] : 0.f;
          for (int i2 = 0; i2 < j; ++i2) {
            float a1 = (k1 < N) ? Q[i2][k1] : 0.f;
            float a2 = (k2 < N) ? Q[i2][k2] : 0.f;
            float p = wave_sum64(vj1 * a1 + vj2 * a2);
            vj1 -= p * a1; vj2 -= p * a2;
          }
          float nn2 = wave_sum64(vj1 * vj1 + vj2 * vj2);
          float inv = rsqrtf(fmaxf(nn2, 1e-33f));
          vj1 *= inv; vj2 *= inv;
          if (k1 < N) Q[j][k1] = vj1;
          if (k2 < N) Q[j][k2] = vj2;
        }
      }
      __syncthreads();
    }
  }
  // H = Q^T (G Q)
  if (tid < R * R) {
    int i = tid / R, j = tid - i * R;
    float s = 0.f;
    for (int k = 0; k < N; ++k) s = fmaf(Q[i][k], Wm[j][k], s);
    H[i * R + j] = s;
  }
  __syncthreads();
  // Jacobi eigh of H (RxR), 5 cyclic sweeps (H near-diagonal when warm)
  if (tid == 0) {
    float A[R][R], V[R][R];
    for (int i = 0; i < R; ++i)
      for (int j = 0; j < R; ++j) { A[i][j] = H[i * R + j]; V[i][j] = (i == j) ? 1.f : 0.f; }
    for (int sw = 0; sw < 5; ++sw)
      for (int p = 0; p < R - 1; ++p)
        for (int qj = p + 1; qj < R; ++qj) {
          float apq = A[p][qj];
          if (fabsf(apq) < 1e-12f) continue;
          float theta = 0.5f * (A[qj][qj] - A[p][p]) / apq;
          float t = ((theta >= 0.f) ? 1.f : -1.f) / (fabsf(theta) + sqrtf(theta * theta + 1.f));
          float c = rsqrtf(t * t + 1.f);
          float s = t * c;
          for (int k2 = 0; k2 < R; ++k2) {
            float akp = A[k2][p], akq = A[k2][qj];
            A[k2][p] = c * akp - s * akq;
            A[k2][qj] = s * akp + c * akq;
          }
          for (int k2 = 0; k2 < R; ++k2) {
            float apk = A[p][k2], aqk = A[qj][k2];
            A[p][k2] = c * apk - s * aqk;
            A[qj][k2] = s * apk + c * aqk;
          }
          for (int k2 = 0; k2 < R; ++k2) {
            float vkp = V[k2][p], vkq = V[k2][qj];
            V[k2][p] = c * vkp - s * vkq;
            V[k2][qj] = s * vkp + c * vkq;
          }
        }
    int ord[R];
    for (int i = 0; i < R; ++i) ord[i] = i;
    for (int i = 0; i < R; ++i) {
      int mi = i;
      for (int j = i + 1; j < R; ++j)
        if (A[ord[j]][ord[j]] > A[ord[mi]][ord[mi]]) mi = j;
      int t2 = ord[i]; ord[i] = ord[mi]; ord[mi] = t2;
    }
    for (int i = 0; i < R; ++i)
      for (int j = 0; j < R; ++j) U[j * R + i] = V[j][ord[i]];
  }
  __syncthreads();
  for (int idx = tid; idx < N * R; idx += TH) {
    int k = idx / R, i = idx - k * R;
    float s = 0.f;
#pragma unroll
    for (int j = 0; j < R; ++j) s = fmaf(U[j * R + i], Q[j][k], s);
    Wm[i][k] = s;
  }
  __syncthreads();
  for (int vec = wv; vec < R; vec += WAVES) {
    float* v = &Wm[vec][0];
    float ma = -1.f; int mi = 0x7fffffff;
    for (int k = lane; k < N; k += 64) {
      float a = fabsf(v[k]);
      if (a > ma || (a == ma && k < mi)) { ma = a; mi = k; }
    }
#pragma unroll
    for (int off = 32; off > 0; off >>= 1) {
      float oa = __shfl_down(ma, off, 64);
      int oi = __shfl_down(mi, off, 64);
      if (oa > ma || (oa == ma && oi < mi)) { ma = oa; mi = oi; }
    }
    mi = __shfl(mi, 0, 64);
    float sg = (v[mi] < 0.f) ? -1.f : 1.f;
    for (int k = lane; k < N; k += 64) F[k * R + vec] = sg * v[k];
  }
}

// ---------------------------------------------------------------------------
extern "C" void kernel_launch(void* const* d_in, const int* in_sizes, int n_in,
                              void* d_out, int out_size, void* d_ws, size_t ws_size,
                              hipStream_t stream) {
  (void)in_sizes; (void)n_in; (void)out_size; (void)ws_size;
  const float* x  = (const float*)d_in[0];
  const float* cw = (const float*)d_in[1];
  const float* cb = (const float*)d_in[2];
  float* out = (float*)d_out;
  float* ws  = (float*)d_ws;

  float* T    = ws + OFF_T;
  float* TC   = ws + OFF_TC;
  float* TB   = ws + OFF_TB;
  float* PART = ws + OFF_PART;
  float* P2   = ws + OFF_P2;
  float* TD0a = ws + OFF_TD0a;
  float* TD0b = ws + OFF_TD0b;
  float* TD   = ws + OFF_TD;
  float* G0   = ws + OFF_G0;
  float* G1   = ws + OFF_G1;
  float* G2   = ws + OFF_G2;
  float* G3   = ws + OFF_G3;
  float* F0   = ws + OFF_F0;
  float* F1   = ws + OFF_F1;
  float* F2   = ws + OFF_F2;
  float* F3   = ws + OFF_F3;

  kconv<<<(26214400 + 255) / 256, 256, 0, stream>>>(x, cw, cb, T);

  // ---- HOSVD init: 3 grams + two-stage reduces ----
  kgram_big<100, 8192, false><<<640, 256, 0, stream>>>(T, PART, 32);
  kreduce1<<<RED_K * 40, 256, 0, stream>>>(PART, P2, 10000, 640);
  kreduce2<<<40, 256, 0, stream>>>(P2, G1, 10000);
  kgram_big<128, 64, false><<<400, 256, 0, stream>>>(T, PART, 3200);
  kreduce1<<<RED_K * 64, 256, 0, stream>>>(PART, P2, 16384, 400);
  kreduce2<<<64, 256, 0, stream>>>(P2, G2, 16384);
  kgram_big<64, 1, true><<<1536, 256, 0, stream>>>(T, PART, 409600);
  kreduce1<<<RED_K * 16, 256, 0, stream>>>(PART, P2, 4096, 1536);
  kreduce2<<<16, 256, 0, stream>>>(P2, G3, 4096);

  keigh_init<<<3, 1024, 0, stream>>>(G1, F1, G2, F2, G3, F3);

  // ---- HOOI sweeps: 4 sweeps. sweep 0: STEPS=3 (HOSVD warm starts);
  //      sweeps 1-2: STEPS=2; sweep 3: STEPS=4 (accuracy anchor) ----
  for (int sweep = 0; sweep < 4; ++sweep) {
    const bool first = (sweep == 0);
    const bool last  = (sweep == 3);
    // mode 0
    kcontract<6, 8192><<<1024, 256, 0, stream>>>(T, F1, TB, 32, 100);
    kcontract<6, 64><<<48, 256, 0, stream>>>(TB, F2, TD0a, 192, 128);
    kcontract<6, 1><<<5, 256, 0, stream>>>(TD0a, F3, TD0b, 1152, 64);
    kgram_small<<<4, 256, 0, stream>>>(TD0b, G0, 1, 32, 216);
    if (first)     keigh_one<32, 8, 256><<<1, 256, 0, stream>>>(G0, F0);
    else if (last) ksub<32, 8, 256, 4><<<1, 256, 0, stream>>>(G0, F0);
    else           ksub<32, 8, 256, 2><<<1, 256, 0, stream>>>(G0, F0);
    // TC = T x0 F0 (reused by modes 1,2,3 and the final core)
    kcontract<8, 819200><<<3200, 256, 0, stream>>>(T, F0, TC, 1, 32);
    // mode 1
    kcontract<6, 64><<<200, 256, 0, stream>>>(TC, F2, TB, 800, 128);
    kcontract<6, 1><<<19, 256, 0, stream>>>(TB, F3, TD, 4800, 64);
    kgram_small<<<40, 256, 0, stream>>>(TD, G0, 8, 100, 36);
    if (first)     ksub<100, 6, 1024, 3><<<1, 1024, 0, stream>>>(G0, F1);
    else if (last) ksub<100, 6, 1024, 4><<<1, 1024, 0, stream>>>(G0, F1);
    else           ksub<100, 6, 1024, 2><<<1, 1024, 0, stream>>>(G0, F1);
    // mode 2 (TB = TC x1 F1 also reused by mode 3 AND the final core)
    kcontract<6, 8192><<<256, 256, 0, stream>>>(TC, F1, TB, 8, 100);
    kcontract<6, 1><<<24, 256, 0, stream>>>(TB, F3, TD, 6144, 64);
    kgram_small<<<64, 256, 0, stream>>>(TD, G0, 48, 128, 6);
    if (first)     ksub<128, 6, 1024, 3><<<1, 1024, 0, stream>>>(G0, F2);
    else if (last) ksub<128, 6, 1024, 4><<<1, 1024, 0, stream>>>(G0, F2);
    else           ksub<128, 6, 1024, 2><<<1, 1024, 0, stream>>>(G0, F2);
    // mode 3 (reuses TB; its TD = TB x2 F2 is ALSO the final core's TD)
    kcontract<6, 64><<<12, 256, 0, stream>>>(TB, F2, TD, 48, 128);
    kgram_small<<<16, 256, 0, stream>>>(TD, G0, 288, 64, 1);
    if (first)     ksub<64, 6, 512, 3><<<1, 512, 0, stream>>>(G0, F3);
    else if (last) ksub<64, 6, 512, 4><<<1, 512, 0, stream>>>(G0, F3);
    else           ksub<64, 6, 512, 2><<<1, 512, 0, stream>>>(G0, F3);
  }

  // ---- core: TB (= TC x1 F1) and TD (= TB x2 F2) already hold last-sweep
  //      mode-2/3 outputs with the final F1/F2 -> only the F3 contraction ----
  kcontract<6, 1><<<2, 256, 0, stream>>>(TD, F3, out, 288, 64);
}